// Round 11
// baseline (280.154 us; speedup 1.0000x reference)
//
#include <hip/hip_runtime.h>
#include <cstdint>
#include <cstddef>

typedef __bf16 bf16x8 __attribute__((ext_vector_type(8)));
typedef float  f32x4  __attribute__((ext_vector_type(4)));
typedef int    i32x4  __attribute__((ext_vector_type(4)));

#define QMAX 7.0f
#define SCALE_MIN 2e-16f

#define BAR()     asm volatile("s_barrier" ::: "memory")
#define WAITVM(N) asm volatile("s_waitcnt vmcnt(" #N ")" ::: "memory")
#define LGKM0()   do { asm volatile("s_waitcnt lgkmcnt(0)" ::: "memory"); \
                       __builtin_amdgcn_sched_barrier(0); } while (0)

// ---------------------------------------------------------------------------
// Kernel 1: per-output-channel fake-quant of w [256,256,3,3] -> bf16 wq[tap][o][c]
// ---------------------------------------------------------------------------
__global__ __launch_bounds__(256) void quant_w_kernel(const float* __restrict__ w,
                                                      __bf16* __restrict__ wq) {
    const int o = blockIdx.x;
    const int t = threadIdx.x;
    const float* wo = w + (size_t)o * 2304;

    float vals[9];
    float m = 0.f;
    #pragma unroll
    for (int i = 0; i < 9; ++i) {
        float v = wo[t + i * 256];
        vals[i] = v;
        m = fmaxf(m, fabsf(v));
    }
    #pragma unroll
    for (int off = 32; off >= 1; off >>= 1) m = fmaxf(m, __shfl_down(m, off));
    __shared__ float red[4];
    __shared__ float s_scale;
    if ((t & 63) == 0) red[t >> 6] = m;
    __syncthreads();
    if (t == 0) {
        float am = fmaxf(fmaxf(red[0], red[1]), fmaxf(red[2], red[3]));
        s_scale = fmaxf(am / QMAX, SCALE_MIN);
    }
    __syncthreads();
    const float scale = s_scale;

    #pragma unroll
    for (int i = 0; i < 9; ++i) {
        int idx = t + i * 256;           // = c*9 + tap
        int c = idx / 9;
        int tap = idx - c * 9;
        float q = rintf(vals[i] / scale);          // round-half-even, matches jnp.round
        q = fminf(QMAX, fmaxf(-QMAX, q));
        wq[(size_t)tap * 65536 + (size_t)o * 256 + c] = (__bf16)(q * scale);
    }
}

// ---------------------------------------------------------------------------
// Kernel 2: x NCHW fp32 [32,256,56,56] -> padded NHWC bf16 [32][58][58][256]
// ---------------------------------------------------------------------------
__global__ __launch_bounds__(256) void convert_x_kernel(const float* __restrict__ x,
                                                        __bf16* __restrict__ xpad) {
    __shared__ float tile[32][33];
    const int n  = blockIdx.z;
    const int c0 = blockIdx.y * 32;
    const int p0 = blockIdx.x * 32;
    const int tx = threadIdx.x & 31;
    const int ty = threadIdx.x >> 5;

    #pragma unroll
    for (int r = 0; r < 4; ++r) {
        int c = c0 + ty + r * 8;
        tile[ty + r * 8][tx] = x[((size_t)(n * 256 + c)) * 3136 + p0 + tx];
    }
    __syncthreads();
    #pragma unroll
    for (int r = 0; r < 4; ++r) {
        int p = p0 + ty + r * 8;
        int h = p / 56, wcol = p - h * 56;
        xpad[(((size_t)n * 58 + h + 1) * 58 + (wcol + 1)) * 256 + c0 + tx] =
            (__bf16)tile[tx][ty + r * 8];
    }
}

// ---------------------------------------------------------------------------
// Kernel 2b: zero the 1-cell halo of xpad.
// ---------------------------------------------------------------------------
__global__ __launch_bounds__(256) void zero_halo_kernel(__bf16* __restrict__ xpad) {
    const int t = blockIdx.x * 256 + threadIdx.x;
    const int cvec = t & 31;
    const int r    = t >> 5;
    const int n    = r / 228;
    const int pos  = r - n * 228;
    if (n >= 32) return;
    int h, wcol;
    if      (pos < 58)  { h = 0;          wcol = pos; }
    else if (pos < 116) { h = 57;         wcol = pos - 58; }
    else if (pos < 172) { h = pos - 115;  wcol = 0; }
    else                { h = pos - 171;  wcol = 57; }
    i32x4* dst = (i32x4*)(xpad + (((size_t)n * 58 + h) * 58 + wcol) * 256);
    dst[cvec] = (i32x4){0, 0, 0, 0};
}

// ---------------------------------------------------------------------------
// Kernel 3: implicit-GEMM conv — faithful 8-phase 256^2 schedule (m201 port).
// Tile 256o x 256pos, 512 thr, 8 waves (wm=wv>>2 in {0,1}: o-half; wn=wv&3:
// pos-quarter), per-wave 128x64, mfma_16x16x32, BK=64, 36 K-tiles, 18 iters.
// LDS 128 KB = 2 buffers x (A 32K | B 32K), 1 block/CU.
// Per iteration (K-tiles T=2i from buf0, T+1 from buf1), 8 phases; each phase:
//   [ds_reads] [2 gload_lds] BAR [lgkm(0)+sched_barrier] setprio1 16-MFMA
//   setprio0 BAR.
// Reads front-loaded: ph1: A ks0 (8) + B ks0+ks1 (8); ph3: A ks1 (8) ->
// buffer fully read after ph3. Staging rotation (all race-checked):
//   ph1: A34(T+1)->b1 | ph2: B12(T+2)->b0 | ph3: B34(T+2) | ph4: A12(T+2),
//   WAITVM(6) [=> T+1 fully landed before ph5] | ph5: A34(T+2) |
//   ph6: B12(T+3)->b1 | ph7: B34(T+3) | ph8: A12(T+3), WAITVM(6)
//   [=> T+2 fully landed before next ph1].  Every load >=3 phases in flight.
// LDS layout (128B rows of 64 K-elems): stored K-half = ks ^ (row&1), stored
// 16B-chunk = c ^ ((row>>1)&3): each 16-lane quarter of a frag ds_read_b128
// covers all 32 banks exactly 2-way (free). Staging source pre-swizzle is
// thread-uniform: ks^=((t>>2)^(t>>3))&1, c^=(t>>4)&3; gload_lds dest linear.
// Grid 392 = 8*49 XCD-bijective (2 dispatch rounds; accepted imbalance).
// ---------------------------------------------------------------------------
__device__ __forceinline__ void gload_lds16(const void* g, void* l) {
    __builtin_amdgcn_global_load_lds((const __attribute__((address_space(1))) void*)g,
                                     (__attribute__((address_space(3))) void*)l,
                                     16, 0, 0);
}

__global__ __launch_bounds__(512, 2) void conv_mfma_kernel(const __bf16* __restrict__ xpad,
                                                           const __bf16* __restrict__ wq,
                                                           float* __restrict__ out) {
    extern __shared__ __align__(16) char lds[];   // 131072 B
    const int tid  = threadIdx.x;
    const int wv   = tid >> 6;          // 0..7
    const int lane = tid & 63;
    const int l15  = lane & 15;
    const int bid  = blockIdx.x;
    const int swz  = (bid & 7) * 49 + (bid >> 3);    // 392 = 8*49 bijection
    const int p0   = swz * 256;

    const int wm = wv >> 2;        // 0..1 : o 128-half
    const int wn = wv & 3;         // 0..3 : pos 64-quarter

    // ---- staging source setup (per-thread, swizzle pre-applied) ----------
    const int srow = tid >> 3;                               // 0..63
    const int sks  = ((tid >> 2) ^ (tid >> 3)) & 1;          // logical K-half
    const int slch = (tid & 3) ^ ((tid >> 4) & 3);           // logical chunk
    const int soffk = sks * 32 + slch * 8;                   // elems within 64
    const __bf16* pA[4];
    #pragma unroll
    for (int j = 0; j < 4; ++j)
        pA[j] = wq + (size_t)(j * 64 + srow) * 256 + soffk;
    const __bf16* pB[4];
    #pragma unroll
    for (int j = 0; j < 4; ++j) {
        int pos = p0 + j * 64 + srow;                        // < 100352 exact
        int ni = pos / 3136;
        int hw = pos - ni * 3136;
        int h = hw / 56, w = hw - h * 56;
        pB[j] = xpad + (((size_t)ni * 58 + h) * 58 + w) * 256 + soffk;
    }
    // wave-uniform LDS dest bases (HW adds lane*16); A at +0, B at +32768
    const int wdst = wv * 1024;

    // ---- fragment read bases (swizzled) ----------------------------------
    const int swzc = ((lane >> 4) ^ ((l15 >> 1) & 3)) * 16;
    const int aRd0 = (wm * 128 + l15) * 128 + swzc;              // + m*2048 + kx
    const int bRd0 = 32768 + (wn * 64 + l15) * 128 + swzc;       // + n*2048 + kx
    int kx[2];
    kx[0] = (l15 & 1) * 64;          // stored half for logical ks=0
    kx[1] = (1 - (l15 & 1)) * 64;    // logical ks=1

    f32x4 acc[8][4];
    #pragma unroll
    for (int m = 0; m < 8; ++m)
        #pragma unroll
        for (int n = 0; n < 4; ++n)
            acc[m][n] = (f32x4){0.f, 0.f, 0.f, 0.f};

    char* const b0 = lds;
    char* const b1 = lds + 65536;

    // stage macros: one 8KB block-load (1 instr/wave)
    #define STG_A(KT, J, BUF)                                                   \
        gload_lds16(pA[J] + ((size_t)((KT) >> 2) * 65536 + ((KT) & 3) * 64),    \
                    (BUF) + (J) * 8192 + wdst)
    #define STG_B(KT, J, BUF)                                                   \
        gload_lds16(pB[J] + ((size_t)((((KT) >> 2) / 3) * 58 + (((KT) >> 2) % 3)) * 256 \
                            + ((KT) & 3) * 64),                                 \
                    (BUF) + 32768 + (J) * 8192 + wdst)

    // ---- prologue: K0 fully (8), K1 B12,B34,A12 (6); canonical FIFO ------
    STG_B(0, 0, b0); STG_B(0, 1, b0); STG_B(0, 2, b0); STG_B(0, 3, b0);
    STG_A(0, 0, b0); STG_A(0, 1, b0); STG_A(0, 2, b0); STG_A(0, 3, b0);
    STG_B(1, 0, b1); STG_B(1, 1, b1); STG_B(1, 2, b1); STG_B(1, 3, b1);
    STG_A(1, 0, b1); STG_A(1, 1, b1);
    WAITVM(6);                                   // K0 landed; K1 partial in flight
    BAR();

    bf16x8 a[8], b[4][2];

    #pragma unroll 1
    for (int i = 0; i < 18; ++i) {
        const int T = 2 * i;
        const bool g2 = (T + 2 < 36);
        const bool g3 = (T + 3 < 36);
        const bool lastw = (i == 17);

        // ===== ph1: reads b0{A ks0, B ks0+ks1}; stage A34(T+1)->b1 =====
        #pragma unroll
        for (int m = 0; m < 8; ++m)
            a[m] = *(const bf16x8*)(b0 + aRd0 + m * 2048 + kx[0]);
        #pragma unroll
        for (int n = 0; n < 4; ++n) {
            b[n][0] = *(const bf16x8*)(b0 + bRd0 + n * 2048 + kx[0]);
            b[n][1] = *(const bf16x8*)(b0 + bRd0 + n * 2048 + kx[1]);
        }
        STG_A(T + 1, 2, b1); STG_A(T + 1, 3, b1);
        BAR(); LGKM0();
        __builtin_amdgcn_s_setprio(1);
        #pragma unroll
        for (int m = 0; m < 8; ++m) {
            acc[m][0] = __builtin_amdgcn_mfma_f32_16x16x32_bf16(a[m], b[0][0], acc[m][0], 0, 0, 0);
            acc[m][1] = __builtin_amdgcn_mfma_f32_16x16x32_bf16(a[m], b[1][0], acc[m][1], 0, 0, 0);
        }
        __builtin_amdgcn_s_setprio(0);
        BAR();

        // ===== ph2: stage B12(T+2)->b0 ; MFMA ks0 n23 =====
        if (g2) { STG_B(T + 2, 0, b0); STG_B(T + 2, 1, b0); }
        BAR();
        __builtin_amdgcn_s_setprio(1);
        #pragma unroll
        for (int m = 0; m < 8; ++m) {
            acc[m][2] = __builtin_amdgcn_mfma_f32_16x16x32_bf16(a[m], b[2][0], acc[m][2], 0, 0, 0);
            acc[m][3] = __builtin_amdgcn_mfma_f32_16x16x32_bf16(a[m], b[3][0], acc[m][3], 0, 0, 0);
        }
        __builtin_amdgcn_s_setprio(0);
        BAR();

        // ===== ph3: reads b0{A ks1}; stage B34(T+2)->b0 ; MFMA ks1 n01 =====
        #pragma unroll
        for (int m = 0; m < 8; ++m)
            a[m] = *(const bf16x8*)(b0 + aRd0 + m * 2048 + kx[1]);
        if (g2) { STG_B(T + 2, 2, b0); STG_B(T + 2, 3, b0); }
        BAR(); LGKM0();
        __builtin_amdgcn_s_setprio(1);
        #pragma unroll
        for (int m = 0; m < 8; ++m) {
            acc[m][0] = __builtin_amdgcn_mfma_f32_16x16x32_bf16(a[m], b[0][1], acc[m][0], 0, 0, 0);
            acc[m][1] = __builtin_amdgcn_mfma_f32_16x16x32_bf16(a[m], b[1][1], acc[m][1], 0, 0, 0);
        }
        __builtin_amdgcn_s_setprio(0);
        BAR();

        // ===== ph4: stage A12(T+2)->b0 ; WAITVM ; MFMA ks1 n23 =====
        if (g2) { STG_A(T + 2, 0, b0); STG_A(T + 2, 1, b0); }
        if (!lastw) { WAITVM(6); } else { WAITVM(0); }   // T+1 fully landed
        BAR();
        __builtin_amdgcn_s_setprio(1);
        #pragma unroll
        for (int m = 0; m < 8; ++m) {
            acc[m][2] = __builtin_amdgcn_mfma_f32_16x16x32_bf16(a[m], b[2][1], acc[m][2], 0, 0, 0);
            acc[m][3] = __builtin_amdgcn_mfma_f32_16x16x32_bf16(a[m], b[3][1], acc[m][3], 0, 0, 0);
        }
        __builtin_amdgcn_s_setprio(0);
        BAR();

        // ===== ph5: reads b1{A ks0, B ks0+ks1}; stage A34(T+2)->b0 =====
        #pragma unroll
        for (int m = 0; m < 8; ++m)
            a[m] = *(const bf16x8*)(b1 + aRd0 + m * 2048 + kx[0]);
        #pragma unroll
        for (int n = 0; n < 4; ++n) {
            b[n][0] = *(const bf16x8*)(b1 + bRd0 + n * 2048 + kx[0]);
            b[n][1] = *(const bf16x8*)(b1 + bRd0 + n * 2048 + kx[1]);
        }
        if (g2) { STG_A(T + 2, 2, b0); STG_A(T + 2, 3, b0); }
        BAR(); LGKM0();
        __builtin_amdgcn_s_setprio(1);
        #pragma unroll
        for (int m = 0; m < 8; ++m) {
            acc[m][0] = __builtin_amdgcn_mfma_f32_16x16x32_bf16(a[m], b[0][0], acc[m][0], 0, 0, 0);
            acc[m][1] = __builtin_amdgcn_mfma_f32_16x16x32_bf16(a[m], b[1][0], acc[m][1], 0, 0, 0);
        }
        __builtin_amdgcn_s_setprio(0);
        BAR();

        // ===== ph6: stage B12(T+3)->b1 ; MFMA ks0 n23 =====
        if (g3) { STG_B(T + 3, 0, b1); STG_B(T + 3, 1, b1); }
        BAR();
        __builtin_amdgcn_s_setprio(1);
        #pragma unroll
        for (int m = 0; m < 8; ++m) {
            acc[m][2] = __builtin_amdgcn_mfma_f32_16x16x32_bf16(a[m], b[2][0], acc[m][2], 0, 0, 0);
            acc[m][3] = __builtin_amdgcn_mfma_f32_16x16x32_bf16(a[m], b[3][0], acc[m][3], 0, 0, 0);
        }
        __builtin_amdgcn_s_setprio(0);
        BAR();

        // ===== ph7: reads b1{A ks1}; stage B34(T+3)->b1 ; MFMA ks1 n01 =====
        #pragma unroll
        for (int m = 0; m < 8; ++m)
            a[m] = *(const bf16x8*)(b1 + aRd0 + m * 2048 + kx[1]);
        if (g3) { STG_B(T + 3, 2, b1); STG_B(T + 3, 3, b1); }
        BAR(); LGKM0();
        __builtin_amdgcn_s_setprio(1);
        #pragma unroll
        for (int m = 0; m < 8; ++m) {
            acc[m][0] = __builtin_amdgcn_mfma_f32_16x16x32_bf16(a[m], b[0][1], acc[m][0], 0, 0, 0);
            acc[m][1] = __builtin_amdgcn_mfma_f32_16x16x32_bf16(a[m], b[1][1], acc[m][1], 0, 0, 0);
        }
        __builtin_amdgcn_s_setprio(0);
        BAR();

        // ===== ph8: stage A12(T+3)->b1 ; WAITVM ; MFMA ks1 n23 =====
        if (g3) { STG_A(T + 3, 0, b1); STG_A(T + 3, 1, b1); }
        if (!lastw) { WAITVM(6); } else { WAITVM(0); }   // T+2 fully landed
        BAR();
        __builtin_amdgcn_s_setprio(1);
        #pragma unroll
        for (int m = 0; m < 8; ++m) {
            acc[m][2] = __builtin_amdgcn_mfma_f32_16x16x32_bf16(a[m], b[2][1], acc[m][2], 0, 0, 0);
            acc[m][3] = __builtin_amdgcn_mfma_f32_16x16x32_bf16(a[m], b[3][1], acc[m][3], 0, 0, 0);
        }
        __builtin_amdgcn_s_setprio(0);
        BAR();
    }
    #undef STG_A
    #undef STG_B

    // ---- epilogue: 16x16 C/D: col(pos)=lane&15, row(o)=(lane>>4)*4 + r ---
    #pragma unroll
    for (int n = 0; n < 4; ++n) {
        const int pos = p0 + wn * 64 + n * 16 + l15;
        const int ni = pos / 3136;
        const int hw = pos - ni * 3136;
        float* ob = out + (size_t)ni * 802816 + hw;
        #pragma unroll
        for (int m = 0; m < 8; ++m) {
            const int om = wm * 128 + m * 16 + (lane >> 4) * 4;
            #pragma unroll
            for (int r = 0; r < 4; ++r)
                ob[(size_t)(om + r) * 3136] = acc[m][n][r];
        }
    }
}

// ---------------------------------------------------------------------------
// Fallback: naive direct conv (only if ws_size too small).
// ---------------------------------------------------------------------------
__global__ __launch_bounds__(256) void conv_naive_kernel(const float* __restrict__ x,
                                                         const float* __restrict__ w,
                                                         float* __restrict__ out) {
    const int n = blockIdx.z;
    const int o = blockIdx.y;
    const int strip = blockIdx.x;
    __shared__ float wqs[2304];
    __shared__ float red[4];
    __shared__ float s_scale;
    const float* wo = w + (size_t)o * 2304;
    float m = 0.f;
    for (int i = threadIdx.x; i < 2304; i += 256) m = fmaxf(m, fabsf(wo[i]));
    #pragma unroll
    for (int off = 32; off >= 1; off >>= 1) m = fmaxf(m, __shfl_down(m, off));
    if ((threadIdx.x & 63) == 0) red[threadIdx.x >> 6] = m;
    __syncthreads();
    if (threadIdx.x == 0) {
        float am = fmaxf(fmaxf(red[0], red[1]), fmaxf(red[2], red[3]));
        s_scale = fmaxf(am / QMAX, SCALE_MIN);
    }
    __syncthreads();
    const float scale = s_scale;
    for (int i = threadIdx.x; i < 2304; i += 256) {
        float q = rintf(wo[i] / scale);
        q = fminf(QMAX, fmaxf(-QMAX, q));
        wqs[i] = q * scale;
    }
    __syncthreads();
    int p = strip * 256 + threadIdx.x;
    if (p >= 3136) return;
    int h = p / 56, wcol = p - h * 56;
    float acc = 0.f;
    for (int c = 0; c < 256; ++c) {
        const float* xc = x + ((size_t)(n * 256 + c)) * 3136;
        const float* wk = wqs + c * 9;
        #pragma unroll
        for (int kh = 0; kh < 3; ++kh) {
            int hh = h + kh - 1;
            if (hh < 0 || hh > 55) continue;
            #pragma unroll
            for (int kw = 0; kw < 3; ++kw) {
                int ww2 = wcol + kw - 1;
                if (ww2 < 0 || ww2 > 55) continue;
                acc += xc[hh * 56 + ww2] * wk[kh * 3 + kw];
            }
        }
    }
    out[((size_t)(n * 256 + o)) * 3136 + p] = acc;
}

// ---------------------------------------------------------------------------
extern "C" void kernel_launch(void* const* d_in, const int* in_sizes, int n_in,
                              void* d_out, int out_size, void* d_ws, size_t ws_size,
                              hipStream_t stream) {
    const float* x = (const float*)d_in[0];
    const float* w = (const float*)d_in[1];
    float* out = (float*)d_out;

    const size_t WQ_BYTES   = 9ull * 256 * 256 * 2;            // 1,179,648
    const size_t XPAD_OFF   = WQ_BYTES;
    const size_t XPAD_BYTES = 32ull * 58 * 58 * 256 * 2;       // 55,083,008

    if (ws_size >= XPAD_OFF + XPAD_BYTES) {
        __bf16* wq   = (__bf16*)d_ws;
        __bf16* xpad = (__bf16*)((char*)d_ws + XPAD_OFF);
        hipFuncSetAttribute((const void*)conv_mfma_kernel,
                            hipFuncAttributeMaxDynamicSharedMemorySize, 131072);
        zero_halo_kernel<<<912, 256, 0, stream>>>(xpad);
        quant_w_kernel<<<256, 256, 0, stream>>>(w, wq);
        convert_x_kernel<<<dim3(98, 8, 32), 256, 0, stream>>>(x, xpad);
        conv_mfma_kernel<<<392, 512, 131072, stream>>>(xpad, wq, out);
    } else {
        conv_naive_kernel<<<dim3(13, 256, 32), 256, 0, stream>>>(x, w, out);
    }
}

// Round 12
// 175.840 us; speedup vs baseline: 1.5932x; 1.5932x over previous
//
#include <hip/hip_runtime.h>
#include <cstdint>
#include <cstddef>

typedef __bf16 bf16x8 __attribute__((ext_vector_type(8)));
typedef float  f32x4  __attribute__((ext_vector_type(4)));
typedef int    i32x4  __attribute__((ext_vector_type(4)));

#define QMAX 7.0f
#define SCALE_MIN 2e-16f

#define BAR()     asm volatile("s_barrier" ::: "memory")
#define WAITVM(N) asm volatile("s_waitcnt vmcnt(" #N ")" ::: "memory")

// ---------------------------------------------------------------------------
// Kernel 1: per-output-channel fake-quant of w [256,256,3,3] -> bf16 wq[tap][o][c]
// ---------------------------------------------------------------------------
__global__ __launch_bounds__(256) void quant_w_kernel(const float* __restrict__ w,
                                                      __bf16* __restrict__ wq) {
    const int o = blockIdx.x;
    const int t = threadIdx.x;
    const float* wo = w + (size_t)o * 2304;

    float vals[9];
    float m = 0.f;
    #pragma unroll
    for (int i = 0; i < 9; ++i) {
        float v = wo[t + i * 256];
        vals[i] = v;
        m = fmaxf(m, fabsf(v));
    }
    #pragma unroll
    for (int off = 32; off >= 1; off >>= 1) m = fmaxf(m, __shfl_down(m, off));
    __shared__ float red[4];
    __shared__ float s_scale;
    if ((t & 63) == 0) red[t >> 6] = m;
    __syncthreads();
    if (t == 0) {
        float am = fmaxf(fmaxf(red[0], red[1]), fmaxf(red[2], red[3]));
        s_scale = fmaxf(am / QMAX, SCALE_MIN);
    }
    __syncthreads();
    const float scale = s_scale;

    #pragma unroll
    for (int i = 0; i < 9; ++i) {
        int idx = t + i * 256;           // = c*9 + tap
        int c = idx / 9;
        int tap = idx - c * 9;
        float q = rintf(vals[i] / scale);          // round-half-even, matches jnp.round
        q = fminf(QMAX, fmaxf(-QMAX, q));
        wq[(size_t)tap * 65536 + (size_t)o * 256 + c] = (__bf16)(q * scale);
    }
}

// ---------------------------------------------------------------------------
// Kernel 2: x NCHW fp32 [32,256,56,56] -> padded NHWC bf16 [32][58][58][256]
// ---------------------------------------------------------------------------
__global__ __launch_bounds__(256) void convert_x_kernel(const float* __restrict__ x,
                                                        __bf16* __restrict__ xpad) {
    __shared__ float tile[32][33];
    const int n  = blockIdx.z;
    const int c0 = blockIdx.y * 32;
    const int p0 = blockIdx.x * 32;
    const int tx = threadIdx.x & 31;
    const int ty = threadIdx.x >> 5;

    #pragma unroll
    for (int r = 0; r < 4; ++r) {
        int c = c0 + ty + r * 8;
        tile[ty + r * 8][tx] = x[((size_t)(n * 256 + c)) * 3136 + p0 + tx];
    }
    __syncthreads();
    #pragma unroll
    for (int r = 0; r < 4; ++r) {
        int p = p0 + ty + r * 8;
        int h = p / 56, wcol = p - h * 56;
        xpad[(((size_t)n * 58 + h + 1) * 58 + (wcol + 1)) * 256 + c0 + tx] =
            (__bf16)tile[tx][ty + r * 8];
    }
}

// ---------------------------------------------------------------------------
// Kernel 2b: zero the 1-cell halo of xpad.
// ---------------------------------------------------------------------------
__global__ __launch_bounds__(256) void zero_halo_kernel(__bf16* __restrict__ xpad) {
    const int t = blockIdx.x * 256 + threadIdx.x;
    const int cvec = t & 31;
    const int r    = t >> 5;
    const int n    = r / 228;
    const int pos  = r - n * 228;
    if (n >= 32) return;
    int h, wcol;
    if      (pos < 58)  { h = 0;          wcol = pos; }
    else if (pos < 116) { h = 57;         wcol = pos - 58; }
    else if (pos < 172) { h = pos - 115;  wcol = 0; }
    else                { h = pos - 171;  wcol = 57; }
    i32x4* dst = (i32x4*)(xpad + (((size_t)n * 58 + h) * 58 + wcol) * 256);
    dst[cvec] = (i32x4){0, 0, 0, 0};
}

// ---------------------------------------------------------------------------
// Kernel 3: implicit-GEMM conv — R7-best chassis, swizzle fixed, ticketed.
// Block 256o x 128pos, 256 thr (4 waves 2Mx2N), PER-WAVE 128x64:
//   8x4 frags of mfma_f32_16x16x32_bf16, 12 ds_read_b128 / 32 MFMA per step.
// BK=32, 72 K-steps. TRIPLE-buffered LDS (3 x 24 KB = 72 KB) -> 2 blocks/CU.
// Per step: STAGE(s+1) 6 gloads at top -> WAITVM(6) counted -> ONE BAR ->
// 12 ds_read + 32 MFMA (compiler-scheduled partial lgkmcnt).
// SWIZZLE (the single change vs the 145.6us R7 run): stored 16B-slot =
// chunk ^ ((row>>1)&3) on 64B rows. A b128 half-wave (32 lanes, rows 0..15,
// chunk=lane>>4) then covers all 8 (row-parity, slot) bank positions at
// exactly 4-way = the b128 minimum (the class R8 measured at 0 conflicts).
// R7's ((row>>3)&1) covered only 4 positions -> 8-way -> 1.084e7 conflicts.
// Staging source pre-swizzle: (tid&3)^((tid>>3)&3) (thread-uniform,
// issue-independent); gload_lds dest stays linear (both-sides rule).
// PERSISTENT: grid 512, atomic ticket over 784 pos-tiles (R9-validated).
// ---------------------------------------------------------------------------
__device__ __forceinline__ void gload_lds16(const void* g, void* l) {
    __builtin_amdgcn_global_load_lds((const __attribute__((address_space(1))) void*)g,
                                     (__attribute__((address_space(3))) void*)l,
                                     16, 0, 0);
}

__global__ __launch_bounds__(256, 2) void conv_mfma_kernel(const __bf16* __restrict__ xpad,
                                                           const __bf16* __restrict__ wq,
                                                           float* __restrict__ out,
                                                           int* __restrict__ ticket) {
    extern __shared__ __align__(16) char lds[];   // 73792 B: 3x24576 + ticket slot
    int* s_t = (int*)(lds + 73728);
    const int tid  = threadIdx.x;
    const int wv   = tid >> 6;          // 0..3
    const int lane = tid & 63;
    const int l15  = lane & 15;

    const int wm = wv >> 1;        // 0..1 : o 128-half
    const int wn = wv & 1;         // 0..1 : pos 64-half

    // ---- staging setup: 6 issues/step of 4 KB (64 rows x 64 B) -----------
    const int trow   = tid >> 2;                     // 0..63 row within issue
    const int schunk = (tid & 3) ^ ((tid >> 3) & 3); // pre-swizzled src slot
    // A-issue j (0..3): o row = j*64 + trow
    const __bf16* pA[4];
    #pragma unroll
    for (int j = 0; j < 4; ++j)
        pA[j] = wq + (size_t)(j * 64 + trow) * 256 + schunk * 8;
    // wave-uniform LDS dest bases (HW adds lane*16):
    const int adst = wv * 1024;            // + j*4096   (A region: 16 KB)
    const int bdst = 16384 + wv * 1024;    // + j*4096   (B region: 8 KB)

    // ---- fragment read offsets -------------------------------------------
    // frag row = <mult of 16> + l15; stored slot = (lane>>4) ^ ((l15>>1)&3).
    const int aoff0 = l15 * 64 + ((((lane >> 4) ^ ((l15 >> 1) & 3))) << 4);
    const int abase = wm * 8192;                      // A rows wm*128.. (+m*1024)
    const int bbase = 16384 + wn * 4096;              // B rows wn*64..  (+n*1024)

    // ---- persistent tile loop --------------------------------------------
    for (;;) {
        __syncthreads();
        if (tid == 0) *s_t = atomicAdd(ticket, 1);
        __syncthreads();
        const int tile = *s_t;
        if (tile >= 784) break;
        const int p0 = tile * 128;

        // B-issue j (0..1): pos = p0 + j*64 + trow
        const __bf16* pBs[2];
        #pragma unroll
        for (int j = 0; j < 2; ++j) {
            int pos = p0 + j * 64 + trow;            // < 100352 (exact tiling)
            int ni = pos / 3136;
            int hw = pos - ni * 3136;
            int h = hw / 56, w = hw - h * 56;
            pBs[j] = xpad + (((size_t)ni * 58 + h) * 58 + w) * 256 + schunk * 8;
        }

        f32x4 acc[8][4];
        #pragma unroll
        for (int m = 0; m < 8; ++m)
            #pragma unroll
            for (int n = 0; n < 4; ++n)
                acc[m][n] = (f32x4){0.f, 0.f, 0.f, 0.f};

        // ---- stage helper: 6 gloads (A0..A3, B0, B1) = 6 vmcnt entries ---
        #define STAGE(STEP, BUF)                                                  \
            {                                                                     \
                const int tap_ = (STEP) >> 3, cc_ = (STEP) & 7;                   \
                const int kh_ = tap_ / 3, kw_ = tap_ - kh_ * 3;                   \
                const size_t aoff_ = (size_t)tap_ * 65536 + cc_ * 32;             \
                const size_t boff_ = (size_t)(kh_ * 58 + kw_) * 256 + cc_ * 32;   \
                gload_lds16(pA[0] + aoff_, (BUF) + adst);                         \
                gload_lds16(pA[1] + aoff_, (BUF) + adst + 4096);                  \
                gload_lds16(pA[2] + aoff_, (BUF) + adst + 8192);                  \
                gload_lds16(pA[3] + aoff_, (BUF) + adst + 12288);                 \
                gload_lds16(pBs[0] + boff_, (BUF) + bdst);                        \
                gload_lds16(pBs[1] + boff_, (BUF) + bdst + 4096);                 \
            }

        STAGE(0, lds);                         // prologue: step 0 -> buf0

        int co = 0;                            // (s%3)*24576
        #pragma unroll 1
        for (int s = 0; s < 72; ++s) {
            int no = co + 24576; if (no == 73728) no = 0;
            if (s < 71) {
                STAGE(s + 1, lds + no);
                WAITVM(6);
            } else {
                WAITVM(0);
            }
            BAR();
            const char* B = lds + co;

            bf16x8 a[4], b[4];
            // ---- phase 0: m0..3 x n0..3 ----
            #pragma unroll
            for (int m = 0; m < 4; ++m)
                a[m] = *(const bf16x8*)(B + abase + m * 1024 + aoff0);
            #pragma unroll
            for (int n = 0; n < 4; ++n)
                b[n] = *(const bf16x8*)(B + bbase + n * 1024 + aoff0);
            __builtin_amdgcn_s_setprio(1);
            #pragma unroll
            for (int m = 0; m < 4; ++m)
                #pragma unroll
                for (int n = 0; n < 4; ++n)
                    acc[m][n] = __builtin_amdgcn_mfma_f32_16x16x32_bf16(a[m], b[n], acc[m][n], 0, 0, 0);
            __builtin_amdgcn_s_setprio(0);
            // ---- phase 1: m4..7 x n0..3 ----
            #pragma unroll
            for (int m = 0; m < 4; ++m)
                a[m] = *(const bf16x8*)(B + abase + (m + 4) * 1024 + aoff0);
            __builtin_amdgcn_s_setprio(1);
            #pragma unroll
            for (int m = 0; m < 4; ++m)
                #pragma unroll
                for (int n = 0; n < 4; ++n)
                    acc[m + 4][n] = __builtin_amdgcn_mfma_f32_16x16x32_bf16(a[m], b[n], acc[m + 4][n], 0, 0, 0);
            __builtin_amdgcn_s_setprio(0);
            co = no;
        }
        #undef STAGE

        // ---- epilogue: 16x16 C/D: col=lane&15, row=(lane>>4)*4 + r -------
        #pragma unroll
        for (int n = 0; n < 4; ++n) {
            const int pos = p0 + wn * 64 + n * 16 + l15;
            const int ni = pos / 3136;
            const int hw = pos - ni * 3136;
            float* ob = out + (size_t)ni * 802816 + hw;
            #pragma unroll
            for (int m = 0; m < 8; ++m) {
                const int om = wm * 128 + m * 16 + (lane >> 4) * 4;
                #pragma unroll
                for (int r = 0; r < 4; ++r)
                    ob[(size_t)(om + r) * 3136] = acc[m][n][r];
            }
        }
    }
}

// ---------------------------------------------------------------------------
// Fallback: naive direct conv (only if ws_size too small).
// ---------------------------------------------------------------------------
__global__ __launch_bounds__(256) void conv_naive_kernel(const float* __restrict__ x,
                                                         const float* __restrict__ w,
                                                         float* __restrict__ out) {
    const int n = blockIdx.z;
    const int o = blockIdx.y;
    const int strip = blockIdx.x;
    __shared__ float wqs[2304];
    __shared__ float red[4];
    __shared__ float s_scale;
    const float* wo = w + (size_t)o * 2304;
    float m = 0.f;
    for (int i = threadIdx.x; i < 2304; i += 256) m = fmaxf(m, fabsf(wo[i]));
    #pragma unroll
    for (int off = 32; off >= 1; off >>= 1) m = fmaxf(m, __shfl_down(m, off));
    if ((threadIdx.x & 63) == 0) red[threadIdx.x >> 6] = m;
    __syncthreads();
    if (threadIdx.x == 0) {
        float am = fmaxf(fmaxf(red[0], red[1]), fmaxf(red[2], red[3]));
        s_scale = fmaxf(am / QMAX, SCALE_MIN);
    }
    __syncthreads();
    const float scale = s_scale;
    for (int i = threadIdx.x; i < 2304; i += 256) {
        float q = rintf(wo[i] / scale);
        q = fminf(QMAX, fmaxf(-QMAX, q));
        wqs[i] = q * scale;
    }
    __syncthreads();
    int p = strip * 256 + threadIdx.x;
    if (p >= 3136) return;
    int h = p / 56, wcol = p - h * 56;
    float acc = 0.f;
    for (int c = 0; c < 256; ++c) {
        const float* xc = x + ((size_t)(n * 256 + c)) * 3136;
        const float* wk = wqs + c * 9;
        #pragma unroll
        for (int kh = 0; kh < 3; ++kh) {
            int hh = h + kh - 1;
            if (hh < 0 || hh > 55) continue;
            #pragma unroll
            for (int kw = 0; kw < 3; ++kw) {
                int ww2 = wcol + kw - 1;
                if (ww2 < 0 || ww2 > 55) continue;
                acc += xc[hh * 56 + ww2] * wk[kh * 3 + kw];
            }
        }
    }
    out[((size_t)(n * 256 + o)) * 3136 + p] = acc;
}

// ---------------------------------------------------------------------------
extern "C" void kernel_launch(void* const* d_in, const int* in_sizes, int n_in,
                              void* d_out, int out_size, void* d_ws, size_t ws_size,
                              hipStream_t stream) {
    const float* x = (const float*)d_in[0];
    const float* w = (const float*)d_in[1];
    float* out = (float*)d_out;

    const size_t WQ_BYTES   = 9ull * 256 * 256 * 2;            // 1,179,648
    const size_t XPAD_OFF   = WQ_BYTES;
    const size_t XPAD_BYTES = 32ull * 58 * 58 * 256 * 2;       // 55,083,008
    const size_t TICKET_OFF = XPAD_OFF + XPAD_BYTES;

    if (ws_size >= TICKET_OFF + 64) {
        __bf16* wq   = (__bf16*)d_ws;
        __bf16* xpad = (__bf16*)((char*)d_ws + XPAD_OFF);
        int* ticket  = (int*)((char*)d_ws + TICKET_OFF);
        hipFuncSetAttribute((const void*)conv_mfma_kernel,
                            hipFuncAttributeMaxDynamicSharedMemorySize, 73792);
        hipMemsetAsync(ticket, 0, 4, stream);                  // reset each launch
        zero_halo_kernel<<<912, 256, 0, stream>>>(xpad);
        quant_w_kernel<<<256, 256, 0, stream>>>(w, wq);
        convert_x_kernel<<<dim3(98, 8, 32), 256, 0, stream>>>(x, xpad);
        conv_mfma_kernel<<<512, 256, 73792, stream>>>(xpad, wq, out, ticket);
    } else {
        conv_naive_kernel<<<dim3(13, 256, 32), 256, 0, stream>>>(x, w, out);
    }
}

// Round 13
// 163.994 us; speedup vs baseline: 1.7083x; 1.0722x over previous
//
#include <hip/hip_runtime.h>
#include <cstdint>
#include <cstddef>

typedef __bf16 bf16x8 __attribute__((ext_vector_type(8)));
typedef float  f32x4  __attribute__((ext_vector_type(4)));
typedef int    i32x4  __attribute__((ext_vector_type(4)));

#define QMAX 7.0f
#define SCALE_MIN 2e-16f

#define BAR()     asm volatile("s_barrier" ::: "memory")
#define WAITVM(N) asm volatile("s_waitcnt vmcnt(" #N ")" ::: "memory")

// ---------------------------------------------------------------------------
// Kernel 1 (fused): blocks 0..255 quantize w -> wq[tap][o][c] (bf16);
// blocks 256..1167 zero the 1-cell halo of xpad. Saves one dispatch.
// ---------------------------------------------------------------------------
__global__ __launch_bounds__(256) void pre_kernel(const float* __restrict__ w,
                                                  __bf16* __restrict__ wq,
                                                  __bf16* __restrict__ xpad) {
    const int t = threadIdx.x;
    if (blockIdx.x < 256) {
        // ---- per-output-channel fake-quant ----
        const int o = blockIdx.x;
        const float* wo = w + (size_t)o * 2304;
        float vals[9];
        float m = 0.f;
        #pragma unroll
        for (int i = 0; i < 9; ++i) {
            float v = wo[t + i * 256];
            vals[i] = v;
            m = fmaxf(m, fabsf(v));
        }
        #pragma unroll
        for (int off = 32; off >= 1; off >>= 1) m = fmaxf(m, __shfl_down(m, off));
        __shared__ float red[4];
        __shared__ float s_scale;
        if ((t & 63) == 0) red[t >> 6] = m;
        __syncthreads();
        if (t == 0) {
            float am = fmaxf(fmaxf(red[0], red[1]), fmaxf(red[2], red[3]));
            s_scale = fmaxf(am / QMAX, SCALE_MIN);
        }
        __syncthreads();
        const float scale = s_scale;
        #pragma unroll
        for (int i = 0; i < 9; ++i) {
            int idx = t + i * 256;           // = c*9 + tap
            int c = idx / 9;
            int tap = idx - c * 9;
            float q = rintf(vals[i] / scale);      // round-half-even == jnp.round
            q = fminf(QMAX, fmaxf(-QMAX, q));
            wq[(size_t)tap * 65536 + (size_t)o * 256 + c] = (__bf16)(q * scale);
        }
    } else {
        // ---- halo zero: 32 images x 228 border cells x 256 bf16 ----
        const int g = (blockIdx.x - 256) * 256 + t;
        const int cvec = g & 31;
        const int r    = g >> 5;
        const int n    = r / 228;
        const int pos  = r - n * 228;
        if (n >= 32) return;
        int h, wcol;
        if      (pos < 58)  { h = 0;          wcol = pos; }
        else if (pos < 116) { h = 57;         wcol = pos - 58; }
        else if (pos < 172) { h = pos - 115;  wcol = 0; }
        else                { h = pos - 171;  wcol = 57; }
        i32x4* dst = (i32x4*)(xpad + (((size_t)n * 58 + h) * 58 + wcol) * 256);
        dst[cvec] = (i32x4){0, 0, 0, 0};
    }
}

// ---------------------------------------------------------------------------
// Kernel 2: x NCHW fp32 [32,256,56,56] -> padded NHWC bf16 [32][58][58][256]
// ---------------------------------------------------------------------------
__global__ __launch_bounds__(256) void convert_x_kernel(const float* __restrict__ x,
                                                        __bf16* __restrict__ xpad) {
    __shared__ float tile[32][33];
    const int n  = blockIdx.z;
    const int c0 = blockIdx.y * 32;
    const int p0 = blockIdx.x * 32;
    const int tx = threadIdx.x & 31;
    const int ty = threadIdx.x >> 5;

    #pragma unroll
    for (int r = 0; r < 4; ++r) {
        int c = c0 + ty + r * 8;
        tile[ty + r * 8][tx] = x[((size_t)(n * 256 + c)) * 3136 + p0 + tx];
    }
    __syncthreads();
    #pragma unroll
    for (int r = 0; r < 4; ++r) {
        int p = p0 + ty + r * 8;
        int h = p / 56, wcol = p - h * 56;
        xpad[(((size_t)n * 58 + h + 1) * 58 + (wcol + 1)) * 256 + c0 + tx] =
            (__bf16)tile[tx][ty + r * 8];
    }
}

// ---------------------------------------------------------------------------
// Kernel 3: implicit-GEMM conv — the session's best-measured configuration.
// Block 256o x 128pos, 256 thr (4 waves 2Mx2N), per-wave 128x64 as 8x4 frags
// of mfma_f32_16x16x32_bf16; 12 ds_read_b128 / 32 MFMA per BK=32 step;
// 72 K-steps. TRIPLE-buffered LDS (3 x 24 KB = 72 KB) -> 2 blocks/CU.
// Per step: STAGE(s+1) 6 gloads at top -> WAITVM(6) counted -> ONE BAR ->
// 12 ds_read + 32 MFMA (compiler partial-lgkmcnt scheduling).
// Swizzle (R12, measured 0 conflicts): stored 16B-slot = chunk ^ ((row>>1)&3)
// on 64B rows; staging source pre-swizzled (tid&3)^((tid>>3)&3); gload_lds
// dest linear (both-sides rule).
// Grid: static 784 = 8*98 XCD-bijective (R12 proved ticket/persistent = null
// in conv and -9us in wall; dynamic CU queue already self-balances).
// ---------------------------------------------------------------------------
__device__ __forceinline__ void gload_lds16(const void* g, void* l) {
    __builtin_amdgcn_global_load_lds((const __attribute__((address_space(1))) void*)g,
                                     (__attribute__((address_space(3))) void*)l,
                                     16, 0, 0);
}

__global__ __launch_bounds__(256, 2) void conv_mfma_kernel(const __bf16* __restrict__ xpad,
                                                           const __bf16* __restrict__ wq,
                                                           float* __restrict__ out) {
    extern __shared__ __align__(16) char lds[];   // 73728 B = 3 x 24576
    const int tid  = threadIdx.x;
    const int wv   = tid >> 6;          // 0..3
    const int lane = tid & 63;
    const int l15  = lane & 15;
    const int bid  = blockIdx.x;
    const int swz  = (bid & 7) * 98 + (bid >> 3);    // 784 = 8*98 bijection
    const int p0   = swz * 128;

    const int wm = wv >> 1;        // 0..1 : o 128-half
    const int wn = wv & 1;         // 0..1 : pos 64-half

    // ---- staging setup: 6 issues/step of 4 KB (64 rows x 64 B) -----------
    const int trow   = tid >> 2;                     // 0..63 row within issue
    const int schunk = (tid & 3) ^ ((tid >> 3) & 3); // pre-swizzled src slot
    const __bf16* pA[4];
    #pragma unroll
    for (int j = 0; j < 4; ++j)
        pA[j] = wq + (size_t)(j * 64 + trow) * 256 + schunk * 8;
    const __bf16* pBs[2];
    #pragma unroll
    for (int j = 0; j < 2; ++j) {
        int pos = p0 + j * 64 + trow;                // < 100352 (exact tiling)
        int ni = pos / 3136;
        int hw = pos - ni * 3136;
        int h = hw / 56, w = hw - h * 56;
        pBs[j] = xpad + (((size_t)ni * 58 + h) * 58 + w) * 256 + schunk * 8;
    }
    // wave-uniform LDS dest bases (HW adds lane*16):
    const int adst = wv * 1024;            // + j*4096   (A region: 16 KB)
    const int bdst = 16384 + wv * 1024;    // + j*4096   (B region: 8 KB)

    // ---- fragment read offsets -------------------------------------------
    // frag row = <mult of 16> + l15; stored slot = (lane>>4) ^ ((l15>>1)&3).
    const int aoff0 = l15 * 64 + ((((lane >> 4) ^ ((l15 >> 1) & 3))) << 4);
    const int abase = wm * 8192;                      // A rows wm*128.. (+m*1024)
    const int bbase = 16384 + wn * 4096;              // B rows wn*64..  (+n*1024)

    f32x4 acc[8][4];
    #pragma unroll
    for (int m = 0; m < 8; ++m)
        #pragma unroll
        for (int n = 0; n < 4; ++n)
            acc[m][n] = (f32x4){0.f, 0.f, 0.f, 0.f};

    // ---- stage helper: 6 gloads (A0..A3, B0, B1) = 6 vmcnt entries -------
    #define STAGE(STEP, BUF)                                                  \
        {                                                                     \
            const int tap_ = (STEP) >> 3, cc_ = (STEP) & 7;                   \
            const int kh_ = tap_ / 3, kw_ = tap_ - kh_ * 3;                   \
            const size_t aoff_ = (size_t)tap_ * 65536 + cc_ * 32;             \
            const size_t boff_ = (size_t)(kh_ * 58 + kw_) * 256 + cc_ * 32;   \
            gload_lds16(pA[0] + aoff_, (BUF) + adst);                         \
            gload_lds16(pA[1] + aoff_, (BUF) + adst + 4096);                  \
            gload_lds16(pA[2] + aoff_, (BUF) + adst + 8192);                  \
            gload_lds16(pA[3] + aoff_, (BUF) + adst + 12288);                 \
            gload_lds16(pBs[0] + boff_, (BUF) + bdst);                        \
            gload_lds16(pBs[1] + boff_, (BUF) + bdst + 4096);                 \
        }

    STAGE(0, lds);                         // prologue: step 0 -> buf0

    int co = 0;                            // (s%3)*24576
    #pragma unroll 1
    for (int s = 0; s < 72; ++s) {
        int no = co + 24576; if (no == 73728) no = 0;
        if (s < 71) {
            STAGE(s + 1, lds + no);
            WAITVM(6);
        } else {
            WAITVM(0);
        }
        BAR();
        const char* B = lds + co;

        bf16x8 a[4], b[4];
        // ---- phase 0: m0..3 x n0..3 ----
        #pragma unroll
        for (int m = 0; m < 4; ++m)
            a[m] = *(const bf16x8*)(B + abase + m * 1024 + aoff0);
        #pragma unroll
        for (int n = 0; n < 4; ++n)
            b[n] = *(const bf16x8*)(B + bbase + n * 1024 + aoff0);
        __builtin_amdgcn_s_setprio(1);
        #pragma unroll
        for (int m = 0; m < 4; ++m)
            #pragma unroll
            for (int n = 0; n < 4; ++n)
                acc[m][n] = __builtin_amdgcn_mfma_f32_16x16x32_bf16(a[m], b[n], acc[m][n], 0, 0, 0);
        __builtin_amdgcn_s_setprio(0);
        // ---- phase 1: m4..7 x n0..3 ----
        #pragma unroll
        for (int m = 0; m < 4; ++m)
            a[m] = *(const bf16x8*)(B + abase + (m + 4) * 1024 + aoff0);
        __builtin_amdgcn_s_setprio(1);
        #pragma unroll
        for (int m = 0; m < 4; ++m)
            #pragma unroll
            for (int n = 0; n < 4; ++n)
                acc[m + 4][n] = __builtin_amdgcn_mfma_f32_16x16x32_bf16(a[m], b[n], acc[m + 4][n], 0, 0, 0);
        __builtin_amdgcn_s_setprio(0);
        co = no;
    }
    #undef STAGE

    // ---- epilogue: 16x16 C/D: col=lane&15, row=(lane>>4)*4 + r -----------
    #pragma unroll
    for (int n = 0; n < 4; ++n) {
        const int pos = p0 + wn * 64 + n * 16 + l15;
        const int ni = pos / 3136;
        const int hw = pos - ni * 3136;
        float* ob = out + (size_t)ni * 802816 + hw;
        #pragma unroll
        for (int m = 0; m < 8; ++m) {
            const int om = wm * 128 + m * 16 + (lane >> 4) * 4;
            #pragma unroll
            for (int r = 0; r < 4; ++r)
                ob[(size_t)(om + r) * 3136] = acc[m][n][r];
        }
    }
}

// ---------------------------------------------------------------------------
// Fallback: naive direct conv (only if ws_size too small).
// ---------------------------------------------------------------------------
__global__ __launch_bounds__(256) void conv_naive_kernel(const float* __restrict__ x,
                                                         const float* __restrict__ w,
                                                         float* __restrict__ out) {
    const int n = blockIdx.z;
    const int o = blockIdx.y;
    const int strip = blockIdx.x;
    __shared__ float wqs[2304];
    __shared__ float red[4];
    __shared__ float s_scale;
    const float* wo = w + (size_t)o * 2304;
    float m = 0.f;
    for (int i = threadIdx.x; i < 2304; i += 256) m = fmaxf(m, fabsf(wo[i]));
    #pragma unroll
    for (int off = 32; off >= 1; off >>= 1) m = fmaxf(m, __shfl_down(m, off));
    if ((threadIdx.x & 63) == 0) red[threadIdx.x >> 6] = m;
    __syncthreads();
    if (threadIdx.x == 0) {
        float am = fmaxf(fmaxf(red[0], red[1]), fmaxf(red[2], red[3]));
        s_scale = fmaxf(am / QMAX, SCALE_MIN);
    }
    __syncthreads();
    const float scale = s_scale;
    for (int i = threadIdx.x; i < 2304; i += 256) {
        float q = rintf(wo[i] / scale);
        q = fminf(QMAX, fmaxf(-QMAX, q));
        wqs[i] = q * scale;
    }
    __syncthreads();
    int p = strip * 256 + threadIdx.x;
    if (p >= 3136) return;
    int h = p / 56, wcol = p - h * 56;
    float acc = 0.f;
    for (int c = 0; c < 256; ++c) {
        const float* xc = x + ((size_t)(n * 256 + c)) * 3136;
        const float* wk = wqs + c * 9;
        #pragma unroll
        for (int kh = 0; kh < 3; ++kh) {
            int hh = h + kh - 1;
            if (hh < 0 || hh > 55) continue;
            #pragma unroll
            for (int kw = 0; kw < 3; ++kw) {
                int ww2 = wcol + kw - 1;
                if (ww2 < 0 || ww2 > 55) continue;
                acc += xc[hh * 56 + ww2] * wk[kh * 3 + kw];
            }
        }
    }
    out[((size_t)(n * 256 + o)) * 3136 + p] = acc;
}

// ---------------------------------------------------------------------------
extern "C" void kernel_launch(void* const* d_in, const int* in_sizes, int n_in,
                              void* d_out, int out_size, void* d_ws, size_t ws_size,
                              hipStream_t stream) {
    const float* x = (const float*)d_in[0];
    const float* w = (const float*)d_in[1];
    float* out = (float*)d_out;

    const size_t WQ_BYTES   = 9ull * 256 * 256 * 2;            // 1,179,648
    const size_t XPAD_OFF   = WQ_BYTES;
    const size_t XPAD_BYTES = 32ull * 58 * 58 * 256 * 2;       // 55,083,008

    if (ws_size >= XPAD_OFF + XPAD_BYTES) {
        __bf16* wq   = (__bf16*)d_ws;
        __bf16* xpad = (__bf16*)((char*)d_ws + XPAD_OFF);
        hipFuncSetAttribute((const void*)conv_mfma_kernel,
                            hipFuncAttributeMaxDynamicSharedMemorySize, 73728);
        pre_kernel<<<1168, 256, 0, stream>>>(w, wq, xpad);     // quant + halo zero
        convert_x_kernel<<<dim3(98, 8, 32), 256, 0, stream>>>(x, xpad);
        conv_mfma_kernel<<<784, 256, 73728, stream>>>(xpad, wq, out);
    } else {
        conv_naive_kernel<<<dim3(13, 256, 32), 256, 0, stream>>>(x, w, out);
    }
}